// Round 17
// baseline (263.190 us; speedup 1.0000x reference)
//
#include <hip/hip_runtime.h>
#include <hip/hip_bf16.h>

#define DM 1024
#define TT 2048
#define NH 16
#define DH 64
#define HD 4096

typedef __attribute__((ext_vector_type(4))) float f32x4;
typedef __attribute__((ext_vector_type(8))) short s16x8;
typedef __attribute__((ext_vector_type(4))) short s16x4;

static __device__ __forceinline__ short f2bf(float f) {
  __hip_bfloat16 h = __float2bfloat16(f);
  return *reinterpret_cast<short*>(&h);
}

typedef const __attribute__((address_space(1))) char* gas1_t;
typedef __attribute__((address_space(3))) char* las3_t;
static __device__ __forceinline__ void glds16(const void* g, void* l) {
  __builtin_amdgcn_global_load_lds((gas1_t)g, (las3_t)l, 16, 0, 0);
}

// ---------------- fused weight transpose + fp32->bf16: 4 weights, 1 launch
__global__ __launch_bounds__(256) void transpose_all_k(
    const float* __restrict__ wqkv, const float* __restrict__ wtail,
    const float* __restrict__ w1,   const float* __restrict__ w2,
    short* __restrict__ oqkv, short* __restrict__ otail,
    short* __restrict__ o1,   short* __restrict__ o2)
{
  __shared__ float tile[32][33];
  int t = blockIdx.x;
  const float* in; short* out; int K, N, nx;
  if (t < 3072)      {          in = wqkv;  out = oqkv;  K = 1024; N = 3072; nx = 96; }
  else if (t < 4096) { t -= 3072; in = wtail; out = otail; K = 1024; N = 1024; nx = 32; }
  else if (t < 8192) { t -= 4096; in = w1;    out = o1;    K = 1024; N = 4096; nx = 128; }
  else               { t -= 8192; in = w2;    out = o2;    K = 4096; N = 1024; nx = 32; }
  const int n0 = (t % nx) * 32, k0 = (t / nx) * 32;
  const int tx = threadIdx.x & 31, ty = threadIdx.x >> 5;
#pragma unroll
  for (int i = 0; i < 4; ++i)
    tile[ty + i * 8][tx] = in[(size_t)(k0 + ty + i * 8) * N + n0 + tx];
  __syncthreads();
#pragma unroll
  for (int i = 0; i < 4; ++i) {
    int n = ty + i * 8;
    out[(size_t)(n0 + n) * K + k0 + tx] = f2bf(tile[tx][n]);
  }
}

// ---------------- LayerNorm: fp32 in -> bf16 out, one block per row (D=1024)
__global__ __launch_bounds__(256) void ln_k(
    const float* __restrict__ x, const float* __restrict__ g,
    const float* __restrict__ b, short* __restrict__ out)
{
  const int row = blockIdx.x;
  const int tid = threadIdx.x;
  const float4 v = ((const float4*)(x + (size_t)row * DM))[tid];
  float s = v.x + v.y + v.z + v.w;
  float q = v.x * v.x + v.y * v.y + v.z * v.z + v.w * v.w;
#pragma unroll
  for (int off = 1; off < 64; off <<= 1) {
    s += __shfl_xor(s, off);
    q += __shfl_xor(q, off);
  }
  __shared__ float ss[4], sq[4];
  const int wave = tid >> 6;
  if ((tid & 63) == 0) { ss[wave] = s; sq[wave] = q; }
  __syncthreads();
  s = ss[0] + ss[1] + ss[2] + ss[3];
  q = sq[0] + sq[1] + sq[2] + sq[3];
  const float mu = s * (1.0f / DM);
  const float var = q * (1.0f / DM) - mu * mu;
  const float rs = rsqrtf(var + 1e-5f);
  const float4 gv = ((const float4*)g)[tid];
  const float4 bv = ((const float4*)b)[tid];
  s16x4 o;
  o[0] = f2bf((v.x - mu) * rs * gv.x + bv.x);
  o[1] = f2bf((v.y - mu) * rs * gv.y + bv.y);
  o[2] = f2bf((v.z - mu) * rs * gv.z + bv.z);
  o[3] = f2bf((v.w - mu) * rs * gv.w + bv.w);
  *(s16x4*)(out + (size_t)row * DM + tid * 4) = o;
}

// ---------------- GEMM pipe (r12-proven): BM=BN=128, BK=64, 8 waves (2m x 4n).
// Counted-vmcnt: per phase { vmcnt(2); s_barrier; 6 ds_reads; stage next pair;
// 8 MFMA }. EPI: 1 = +bias+res -> fp32; 2 = +bias GELU -> bf16; 3 = QKV split.
template<int EPI>
__global__ __launch_bounds__(512, 4) void gemm_pipe(
    const short* __restrict__ A, const short* __restrict__ B,
    const float* __restrict__ bias, const float* __restrict__ res,
    float* __restrict__ outF, short* __restrict__ outB,
    short* __restrict__ outK, short* __restrict__ outV,
    int M, int N, int K)
{
  __shared__ short As[2][2][64 * 64];   // [buf][kh]: 128 rows x 64 B = 8 KB
  __shared__ short Bs[2][2][64 * 64];
  const int tid = threadIdx.x;
  const int wave = tid >> 6, lane = tid & 63;
  const int l15 = lane & 15, lhi = lane >> 4;
  const int bm = blockIdx.x, bn = blockIdx.y;
  const int wr = wave >> 2;            // 0..1: m-group (64 rows)
  const int wc = wave & 3;             // 0..3: n-group (32 cols)
  f32x4 acc[4][2] = {};

  const int srow = tid >> 2;
  const int scs = ((tid & 3) ^ ((srow >> 1) & 3)) * 16;
  const int ldst = srow * 64 + (tid & 3) * 16;
  const char* gA = (const char*)(A + (size_t)(bm * 128 + srow) * K);
  const char* gB = (const char*)(B + (size_t)(bn * 128 + srow) * K);

  const int NT = K >> 6;

  auto stagePair = [&](int buf, int kt, int kh) {
    const size_t go = (size_t)kt * 128 + kh * 64 + scs;
    glds16(gA + go, (char*)As[buf][kh] + ldst);
    glds16(gB + go, (char*)Bs[buf][kh] + ldst);
  };

  stagePair(0, 0, 0);
  stagePair(0, 0, 1);

  int buf = 0;
  for (int t = 0; t < NT; ++t) {
#pragma unroll
    for (int kh = 0; kh < 2; ++kh) {
      const bool more = (t + 1 < NT);
      if (more || kh == 0) asm volatile("s_waitcnt vmcnt(2)" ::: "memory");
      else                 asm volatile("s_waitcnt vmcnt(0)" ::: "memory");
      __builtin_amdgcn_s_barrier();
      __builtin_amdgcn_sched_barrier(0);
      s16x8 af[4], bfv[2];
#pragma unroll
      for (int m = 0; m < 4; ++m) {
        const int row = wr * 64 + m * 16 + l15;
        af[m] = *(const s16x8*)((const char*)As[buf][kh] + row * 64 +
                                ((lhi ^ ((row >> 1) & 3)) << 4));
      }
#pragma unroll
      for (int n = 0; n < 2; ++n) {
        const int row = wc * 32 + n * 16 + l15;
        bfv[n] = *(const s16x8*)((const char*)Bs[buf][kh] + row * 64 +
                                 ((lhi ^ ((row >> 1) & 3)) << 4));
      }
      if (more) stagePair(buf ^ 1, t + 1, kh);
      __builtin_amdgcn_s_setprio(1);
#pragma unroll
      for (int m = 0; m < 4; ++m)
#pragma unroll
        for (int n = 0; n < 2; ++n)
          acc[m][n] = __builtin_amdgcn_mfma_f32_16x16x32_bf16(af[m], bfv[n], acc[m][n], 0, 0, 0);
      __builtin_amdgcn_s_setprio(0);
    }
    buf ^= 1;
  }

  const int rowb = bm * 128 + wr * 64;
  const int colb = bn * 128 + wc * 32;
#pragma unroll
  for (int m = 0; m < 4; ++m) {
#pragma unroll
    for (int n = 0; n < 2; ++n) {
      if (EPI == 3) {
        const int col0 = colb + n * 16;
        const int h = col0 / 192;
        const int c0 = col0 - h * 192;
        const int region = c0 >> 6;           // 0=Q, 1=K, 2=V
        const int d = (c0 & 63) + l15;
        const int row0 = rowb + m * 16 + lhi * 4;
        const int bb = row0 >> 11, tl0 = row0 & 2047;
        const size_t bh = (size_t)bb * NH + h;
        if (region == 2) {
          s16x4 pk;
#pragma unroll
          for (int rr = 0; rr < 4; ++rr) pk[rr] = f2bf(acc[m][n][rr]);
          *(s16x4*)(outV + (bh * 64 + d) * TT + tl0) = pk;
        } else {
          short* dst = (region == 0) ? outB : outK;
          const float qs = (region == 0) ? 0.18033688011112042f : 1.0f;  // 0.125*log2(e)
#pragma unroll
          for (int rr = 0; rr < 4; ++rr)
            dst[(bh * TT + tl0 + rr) * 64 + d] = f2bf(acc[m][n][rr] * qs);
        }
      } else {
        const int col = colb + n * 16 + l15;
        const float bv = bias[col];
#pragma unroll
        for (int rr = 0; rr < 4; ++rr) {
          const int row = rowb + m * 16 + lhi * 4 + rr;
          float v = acc[m][n][rr] + bv;
          if (EPI == 1) {
            v += res[(size_t)row * N + col];
            outF[(size_t)row * N + col] = v;
          } else {
            v = 0.5f * v * (1.0f + erff(v * 0.70710678118f));
            outB[(size_t)row * N + col] = f2bf(v);
          }
        }
      }
    }
  }
}

// ---------------- GEMM pipe-256 (fc1): BM=BN=256, BK=64, 8 waves (2m x 4n),
// per-wave output 128x64 (8 m-frags x 4 n-frags = 32 MFMA per 12 ds_reads).
// Same counted-vmcnt discipline scaled: per phase { vmcnt(4); s_barrier;
// 12 ds_reads; stage next kh-half (4 glds/thread); 32 MFMA }. LDS 128 KB,
// 1 block/CU. Race audit identical to gemm_pipe (reads consumed in-phase).
__global__ __launch_bounds__(512, 2) void gemm_pipe256_gelu(
    const short* __restrict__ A, const short* __restrict__ B,
    const float* __restrict__ bias, short* __restrict__ outB,
    int M, int N, int K)
{
  __shared__ short As[2][2][128 * 64];   // [buf][kh]: 256 rows x 64 B = 16 KB
  __shared__ short Bs[2][2][128 * 64];
  const int tid = threadIdx.x;
  const int wave = tid >> 6, lane = tid & 63;
  const int l15 = lane & 15, lhi = lane >> 4;
  const int bm = blockIdx.x, bn = blockIdx.y;
  const int wr = wave >> 2;             // 0..1: m-group (128 rows)
  const int wc = wave & 3;              // 0..3: n-group (64 cols)
  f32x4 acc[8][4] = {};

  // staging: 2 glds per matrix per kh-half; thread -> rows tid>>2 and 128+(tid>>2)
  const int srow = tid >> 2;
  const int scs = ((tid & 3) ^ ((srow >> 1) & 3)) * 16;   // same bits for row+128
  const char* gA0 = (const char*)(A + (size_t)(bm * 256 + srow) * K);
  const char* gA1 = gA0 + (size_t)128 * K * 2;
  const char* gB0 = (const char*)(B + (size_t)(bn * 256 + srow) * K);
  const char* gB1 = gB0 + (size_t)128 * K * 2;

  const int NT = K >> 6;

  auto stageHalf = [&](int buf, int kt, int kh) {
    const size_t go = (size_t)kt * 128 + kh * 64 + scs;
    char* dA = (char*)As[buf][kh] + tid * 16;
    char* dB = (char*)Bs[buf][kh] + tid * 16;
    glds16(gA0 + go, dA);
    glds16(gA1 + go, dA + 8192);
    glds16(gB0 + go, dB);
    glds16(gB1 + go, dB + 8192);
  };

  stageHalf(0, 0, 0);
  stageHalf(0, 0, 1);

  int buf = 0;
  for (int t = 0; t < NT; ++t) {
#pragma unroll
    for (int kh = 0; kh < 2; ++kh) {
      const bool more = (t + 1 < NT);
      if (more || kh == 0) asm volatile("s_waitcnt vmcnt(4)" ::: "memory");
      else                 asm volatile("s_waitcnt vmcnt(0)" ::: "memory");
      __builtin_amdgcn_s_barrier();
      __builtin_amdgcn_sched_barrier(0);
      s16x8 af[8], bfv[4];
#pragma unroll
      for (int m = 0; m < 8; ++m) {
        const int row = wr * 128 + m * 16 + l15;
        af[m] = *(const s16x8*)((const char*)As[buf][kh] + row * 64 +
                                ((lhi ^ ((row >> 1) & 3)) << 4));
      }
#pragma unroll
      for (int n = 0; n < 4; ++n) {
        const int row = wc * 64 + n * 16 + l15;
        bfv[n] = *(const s16x8*)((const char*)Bs[buf][kh] + row * 64 +
                                 ((lhi ^ ((row >> 1) & 3)) << 4));
      }
      if (more) stageHalf(buf ^ 1, t + 1, kh);
      __builtin_amdgcn_s_setprio(1);
#pragma unroll
      for (int m = 0; m < 8; ++m)
#pragma unroll
        for (int n = 0; n < 4; ++n)
          acc[m][n] = __builtin_amdgcn_mfma_f32_16x16x32_bf16(af[m], bfv[n], acc[m][n], 0, 0, 0);
      __builtin_amdgcn_s_setprio(0);
    }
    buf ^= 1;
  }

  const int rowb = bm * 256 + wr * 128;
  const int colb = bn * 256 + wc * 64;
#pragma unroll
  for (int m = 0; m < 8; ++m) {
#pragma unroll
    for (int n = 0; n < 4; ++n) {
      const int col = colb + n * 16 + l15;
      const float bv = bias[col];
#pragma unroll
      for (int rr = 0; rr < 4; ++rr) {
        const int row = rowb + m * 16 + lhi * 4 + rr;
        float v = acc[m][n][rr] + bv;
        v = 0.5f * v * (1.0f + erff(v * 0.70710678118f));
        outB[(size_t)row * N + col] = f2bf(v);
      }
    }
  }
}

// ---------------- flash attention v6 (r10-proven): swapped-QK^T, 16 q/wave,
// KVBLK=64, reg-prefetch staging, log2-softmax + defer-max + padded P.
#define PSTRIDE 144
#define PFRAG   2304
__global__ __launch_bounds__(256, 4) void attn_k(
    const short* __restrict__ Qb, const short* __restrict__ Kb,
    const short* __restrict__ Vtb, const int* __restrict__ mask,
    short* __restrict__ outp)
{
  const int tid = threadIdx.x, wave = tid >> 6, lane = tid & 63;
  const int l15 = lane & 15, lhi = lane >> 4;
  const int lb = blockIdx.x;
  const int bh = lb & 31, qb = lb >> 5;
  const int b = bh >> 4, h = bh & 15;
  const int qw = qb * 64 + wave * 16;

  __shared__ short Ks[64 * 64];
  __shared__ short Vt[64 * 64];
  __shared__ char Ps[4 * PFRAG];

  const short* qp = Qb + ((size_t)bh * TT + qw + l15) * 64;
  const s16x8 aq0 = *(const s16x8*)(qp + lhi * 8);
  const s16x8 aq1 = *(const s16x8*)(qp + 32 + lhi * 8);

  f32x4 o[4] = {};
  float mrow = -1e30f, lrow = 0.f;

  const int kr_s = tid >> 2, kc_s = (tid & 3) * 16;
  const int ksw = (kr_s & 7) << 4;

  const short* kgb = Kb + (size_t)bh * TT * 64 + (size_t)kr_s * 64 + kc_s;
  const short* vgb = Vtb + ((size_t)bh * 64 + kr_s) * TT + kc_s;

  s16x8 kpre[2], vpre[2];
  kpre[0] = *(const s16x8*)kgb;       kpre[1] = *(const s16x8*)(kgb + 8);
  vpre[0] = *(const s16x8*)vgb;       vpre[1] = *(const s16x8*)(vgb + 8);
  int m0 = mask[b * TT + lane];

  char* pb = Ps + wave * PFRAG + l15 * PSTRIDE;

  for (int t0 = 0; t0 < TT; t0 += 64) {
    char* krow = (char*)Ks + kr_s * 128;
    *(s16x8*)(krow + ((kc_s * 2) ^ ksw)) = kpre[0];
    *(s16x8*)(krow + ((kc_s * 2 + 16) ^ ksw)) = kpre[1];
    char* vrow = (char*)Vt + kr_s * 128;
    *(s16x8*)(vrow + ((kc_s * 2) ^ ksw)) = vpre[0];
    *(s16x8*)(vrow + ((kc_s * 2 + 16) ^ ksw)) = vpre[1];
    __syncthreads();

    const unsigned long long mb0 = __ballot(m0 != 0);
    const bool full = mb0 == ~0ULL;

    if (t0 + 64 < TT) {
      const short* kg = kgb + (size_t)(t0 + 64) * 64;
      const short* vg = vgb + t0 + 64;
      kpre[0] = *(const s16x8*)kg;  kpre[1] = *(const s16x8*)(kg + 8);
      vpre[0] = *(const s16x8*)vg;  vpre[1] = *(const s16x8*)(vg + 8);
      m0 = mask[b * TT + t0 + 64 + lane];
    }

    f32x4 sv[4];
    __builtin_amdgcn_s_setprio(1);
#pragma unroll
    for (int n = 0; n < 4; ++n) {
      const int row = n * 16 + l15;
      const int sw = (row & 7) << 4;
      const char* kr = (const char*)Ks + row * 128;
      const s16x8 a0 = *(const s16x8*)(kr + ((lhi * 16) ^ sw));
      const s16x8 a1 = *(const s16x8*)(kr + ((64 + lhi * 16) ^ sw));
      f32x4 z = {};
      z = __builtin_amdgcn_mfma_f32_16x16x32_bf16(a0, aq0, z, 0, 0, 0);
      z = __builtin_amdgcn_mfma_f32_16x16x32_bf16(a1, aq1, z, 0, 0, 0);
      sv[n] = z;
    }
    __builtin_amdgcn_s_setprio(0);

    if (!full) {
#pragma unroll
      for (int n = 0; n < 4; ++n) {
        const unsigned nib = (unsigned)(mb0 >> (n * 16 + lhi * 4)) & 0xF;
#pragma unroll
        for (int rr = 0; rr < 4; ++rr)
          if (!((nib >> rr) & 1)) sv[n][rr] = -3e38f;
      }
    }

    float mx0 = fmaxf(sv[0][0], sv[1][0]), mx1 = fmaxf(sv[0][1], sv[1][1]);
    float mx2 = fmaxf(sv[0][2], sv[1][2]), mx3 = fmaxf(sv[0][3], sv[1][3]);
    mx0 = fmaxf(mx0, fmaxf(sv[2][0], sv[3][0]));
    mx1 = fmaxf(mx1, fmaxf(sv[2][1], sv[3][1]));
    mx2 = fmaxf(mx2, fmaxf(sv[2][2], sv[3][2]));
    mx3 = fmaxf(mx3, fmaxf(sv[2][3], sv[3][3]));
    float mx = fmaxf(fmaxf(mx0, mx1), fmaxf(mx2, mx3));
    mx = fmaxf(mx, __shfl_xor(mx, 16));
    mx = fmaxf(mx, __shfl_xor(mx, 32));
    if (__any(mx > mrow + 8.0f)) {
      const float mn = fmaxf(mrow, mx);
      const float alpha = exp2f(mrow - mn);
      mrow = mn;
      lrow *= alpha;
      float ar[4];
#pragma unroll
      for (int rr = 0; rr < 4; ++rr) ar[rr] = __shfl(alpha, lhi * 4 + rr);
#pragma unroll
      for (int db = 0; db < 4; ++db)
#pragma unroll
        for (int rr = 0; rr < 4; ++rr) o[db][rr] *= ar[rr];
    }
    float s0 = 0.f, s1 = 0.f, s2 = 0.f, s3 = 0.f;
#pragma unroll
    for (int n = 0; n < 4; ++n) {
      sv[n][0] = exp2f(sv[n][0] - mrow); s0 += sv[n][0];
      sv[n][1] = exp2f(sv[n][1] - mrow); s1 += sv[n][1];
      sv[n][2] = exp2f(sv[n][2] - mrow); s2 += sv[n][2];
      sv[n][3] = exp2f(sv[n][3] - mrow); s3 += sv[n][3];
    }
    float sum = (s0 + s1) + (s2 + s3);
    sum += __shfl_xor(sum, 16);
    sum += __shfl_xor(sum, 32);
    lrow += sum;

#pragma unroll
    for (int n = 0; n < 4; ++n) {
      s16x4 pk;
#pragma unroll
      for (int rr = 0; rr < 4; ++rr) pk[rr] = f2bf(sv[n][rr]);
      *(s16x4*)(pb + n * 32 + lhi * 8) = pk;
    }
    asm volatile("s_waitcnt lgkmcnt(0)" ::: "memory");
    __builtin_amdgcn_sched_barrier(0);
    s16x8 ap[2];
    ap[0] = *(const s16x8*)(pb + lhi * 16);
    ap[1] = *(const s16x8*)(pb + 64 + lhi * 16);

    __builtin_amdgcn_s_setprio(1);
#pragma unroll
    for (int db = 0; db < 4; ++db) {
      const int d = db * 16 + l15;
      const int swv = (d & 7) << 4;
      const char* vr2 = (const char*)Vt + d * 128;
#pragma unroll
      for (int ks = 0; ks < 2; ++ks) {
        const s16x8 bv = *(const s16x8*)(vr2 + ((ks * 64 + lhi * 16) ^ swv));
        o[db] = __builtin_amdgcn_mfma_f32_16x16x32_bf16(ap[ks], bv, o[db], 0, 0, 0);
      }
    }
    __builtin_amdgcn_s_setprio(0);
    __syncthreads();
  }

  float lr[4];
#pragma unroll
  for (int rr = 0; rr < 4; ++rr) lr[rr] = __shfl(lrow, lhi * 4 + rr);
#pragma unroll
  for (int db = 0; db < 4; ++db) {
#pragma unroll
    for (int rr = 0; rr < 4; ++rr) {
      const int qg = qw + lhi * 4 + rr;
      const int cg = h * 64 + db * 16 + l15;
      outp[(size_t)(b * TT + qg) * DM + cg] = f2bf(o[db][rr] / lr[rr]);
    }
  }
}

extern "C" void kernel_launch(void* const* d_in, const int* in_sizes, int n_in,
                              void* d_out, int out_size, void* d_ws, size_t ws_size,
                              hipStream_t stream)
{
  const float* x      = (const float*)d_in[0];
  const int*   mask   = (const int*)d_in[1];
  const float* w_qkv  = (const float*)d_in[2];
  const float* w_tail = (const float*)d_in[3];
  const float* b_tail = (const float*)d_in[4];
  const float* ln1g   = (const float*)d_in[5];
  const float* ln1b   = (const float*)d_in[6];
  const float* ln2g   = (const float*)d_in[7];
  const float* ln2b   = (const float*)d_in[8];
  const float* w1     = (const float*)d_in[9];
  const float* b1     = (const float*)d_in[10];
  const float* w2     = (const float*)d_in[11];
  const float* b2     = (const float*)d_in[12];

  char* ws = (char*)d_ws;
  size_t off = 0;
  auto take = [&](size_t bytes) {
    char* p = ws + off;
    off += (bytes + 255) & ~(size_t)255;
    return p;
  };
  short* wqkvT = (short*)take((size_t)3072 * 1024 * 2);   //  6 MB
  short* wtailT= (short*)take((size_t)1024 * 1024 * 2);   //  2 MB
  short* w1T   = (short*)take((size_t)4096 * 1024 * 2);   //  8 MB
  short* w2T   = (short*)take((size_t)1024 * 4096 * 2);   //  8 MB
  short* slotZ = (short*)take((size_t)4096 * 1024 * 2);   //  8 MB
  short* qb    = (short*)take((size_t)32 * 2048 * 64 * 2);//  8 MB
  short* kb    = (short*)take((size_t)32 * 2048 * 64 * 2);//  8 MB
  short* vtb   = (short*)take((size_t)32 * 64 * 2048 * 2);//  8 MB
  float* x1    = (float*)take((size_t)4096 * 1024 * 4);   // 16 MB
  short* hbuf  = (short*)take((size_t)4096 * 4096 * 2);   // 32 MB

  // all weight transposes in one launch
  transpose_all_k<<<12288, 256, 0, stream>>>(w_qkv, w_tail, w1, w2,
                                             wqkvT, wtailT, w1T, w2T);
  // LN1 -> QKV projection (split layout, Q pre-scaled)
  ln_k<<<4096, 256, 0, stream>>>(x, ln1g, ln1b, slotZ);
  gemm_pipe<3><<<dim3(32, 24), 512, 0, stream>>>(slotZ, wqkvT, nullptr, nullptr,
                                                 nullptr, qb, kb, vtb, 4096, 3072, 1024);
  // attention
  attn_k<<<1024, 256, 0, stream>>>(qb, kb, vtb, mask, slotZ);
  // tail projection + residual -> x1 (fp32)
  gemm_pipe<1><<<dim3(32, 8), 512, 0, stream>>>(slotZ, wtailT, b_tail, x,
                                                x1, nullptr, nullptr, nullptr, 4096, 1024, 1024);
  // LN2 -> MLP (fc1 on the 256^2 deep pipe, 256 blocks = 1/CU)
  ln_k<<<4096, 256, 0, stream>>>(x1, ln2g, ln2b, slotZ);
  gemm_pipe256_gelu<<<dim3(16, 16), 512, 0, stream>>>(slotZ, w1T, b1, hbuf,
                                                      4096, 4096, 1024);
  gemm_pipe<1><<<dim3(32, 8), 512, 0, stream>>>(hbuf, w2T, b2, x1,
                                                (float*)d_out, nullptr, nullptr, nullptr, 4096, 1024, 4096);
}

// Round 18
// 255.259 us; speedup vs baseline: 1.0311x; 1.0311x over previous
//
#include <hip/hip_runtime.h>
#include <hip/hip_bf16.h>

#define DM 1024
#define TT 2048
#define NH 16
#define DH 64
#define HD 4096

typedef __attribute__((ext_vector_type(4))) float f32x4;
typedef __attribute__((ext_vector_type(8))) short s16x8;
typedef __attribute__((ext_vector_type(4))) short s16x4;

static __device__ __forceinline__ short f2bf(float f) {
  __hip_bfloat16 h = __float2bfloat16(f);
  return *reinterpret_cast<short*>(&h);
}

typedef const __attribute__((address_space(1))) char* gas1_t;
typedef __attribute__((address_space(3))) char* las3_t;
static __device__ __forceinline__ void glds16(const void* g, void* l) {
  __builtin_amdgcn_global_load_lds((gas1_t)g, (las3_t)l, 16, 0, 0);
}

// ---------------- prep: 4 weight transposes (fp32->bf16 [N][K]) + LN1, fused.
// Blocks 0..12287: transpose tiles. Blocks 12288..16383: LN1 rows.
__global__ __launch_bounds__(256) void prep_k(
    const float* __restrict__ wqkv, const float* __restrict__ wtail,
    const float* __restrict__ w1,   const float* __restrict__ w2,
    short* __restrict__ oqkv, short* __restrict__ otail,
    short* __restrict__ o1,   short* __restrict__ o2,
    const float* __restrict__ x, const float* __restrict__ g,
    const float* __restrict__ bb, short* __restrict__ oz)
{
  int t = blockIdx.x;
  if (t >= 12288) {
    // ---- LayerNorm row
    const int row = t - 12288;
    const int tid = threadIdx.x;
    const float4 v = ((const float4*)(x + (size_t)row * DM))[tid];
    float s = v.x + v.y + v.z + v.w;
    float q = v.x * v.x + v.y * v.y + v.z * v.z + v.w * v.w;
#pragma unroll
    for (int off = 1; off < 64; off <<= 1) {
      s += __shfl_xor(s, off);
      q += __shfl_xor(q, off);
    }
    __shared__ float ss[4], sq[4];
    const int wave = tid >> 6;
    if ((tid & 63) == 0) { ss[wave] = s; sq[wave] = q; }
    __syncthreads();
    s = ss[0] + ss[1] + ss[2] + ss[3];
    q = sq[0] + sq[1] + sq[2] + sq[3];
    const float mu = s * (1.0f / DM);
    const float var = q * (1.0f / DM) - mu * mu;
    const float rs = rsqrtf(var + 1e-5f);
    const float4 gv = ((const float4*)g)[tid];
    const float4 bv = ((const float4*)bb)[tid];
    s16x4 o;
    o[0] = f2bf((v.x - mu) * rs * gv.x + bv.x);
    o[1] = f2bf((v.y - mu) * rs * gv.y + bv.y);
    o[2] = f2bf((v.z - mu) * rs * gv.z + bv.z);
    o[3] = f2bf((v.w - mu) * rs * gv.w + bv.w);
    *(s16x4*)(oz + (size_t)row * DM + tid * 4) = o;
    return;
  }
  // ---- weight transpose tile
  __shared__ float tile[32][33];
  const float* in; short* out; int K, N, nx;
  if (t < 3072)      {          in = wqkv;  out = oqkv;  K = 1024; N = 3072; nx = 96; }
  else if (t < 4096) { t -= 3072; in = wtail; out = otail; K = 1024; N = 1024; nx = 32; }
  else if (t < 8192) { t -= 4096; in = w1;    out = o1;    K = 1024; N = 4096; nx = 128; }
  else               { t -= 8192; in = w2;    out = o2;    K = 4096; N = 1024; nx = 32; }
  const int n0 = (t % nx) * 32, k0 = (t / nx) * 32;
  const int tx = threadIdx.x & 31, ty = threadIdx.x >> 5;
#pragma unroll
  for (int i = 0; i < 4; ++i)
    tile[ty + i * 8][tx] = in[(size_t)(k0 + ty + i * 8) * N + n0 + tx];
  __syncthreads();
#pragma unroll
  for (int i = 0; i < 4; ++i) {
    int n = ty + i * 8;
    out[(size_t)(n0 + n) * K + k0 + tx] = f2bf(tile[tx][n]);
  }
}

// ---------------- LayerNorm: fp32 in -> bf16 out, one block per row (D=1024)
__global__ __launch_bounds__(256) void ln_k(
    const float* __restrict__ x, const float* __restrict__ g,
    const float* __restrict__ b, short* __restrict__ out)
{
  const int row = blockIdx.x;
  const int tid = threadIdx.x;
  const float4 v = ((const float4*)(x + (size_t)row * DM))[tid];
  float s = v.x + v.y + v.z + v.w;
  float q = v.x * v.x + v.y * v.y + v.z * v.z + v.w * v.w;
#pragma unroll
  for (int off = 1; off < 64; off <<= 1) {
    s += __shfl_xor(s, off);
    q += __shfl_xor(q, off);
  }
  __shared__ float ss[4], sq[4];
  const int wave = tid >> 6;
  if ((tid & 63) == 0) { ss[wave] = s; sq[wave] = q; }
  __syncthreads();
  s = ss[0] + ss[1] + ss[2] + ss[3];
  q = sq[0] + sq[1] + sq[2] + sq[3];
  const float mu = s * (1.0f / DM);
  const float var = q * (1.0f / DM) - mu * mu;
  const float rs = rsqrtf(var + 1e-5f);
  const float4 gv = ((const float4*)g)[tid];
  const float4 bv = ((const float4*)b)[tid];
  s16x4 o;
  o[0] = f2bf((v.x - mu) * rs * gv.x + bv.x);
  o[1] = f2bf((v.y - mu) * rs * gv.y + bv.y);
  o[2] = f2bf((v.z - mu) * rs * gv.z + bv.z);
  o[3] = f2bf((v.w - mu) * rs * gv.w + bv.w);
  *(s16x4*)(out + (size_t)row * DM + tid * 4) = o;
}

// ---------------- GEMM pipe (r12-proven): BM=BN=128, BK=64, 8 waves (2m x 4n).
// Counted-vmcnt: per phase { vmcnt(2); s_barrier; 6 ds_reads; stage next pair;
// 8 MFMA }. EPI: 1 = +bias+res -> fp32; 2 = +bias GELU -> bf16; 3 = QKV split.
template<int EPI>
__global__ __launch_bounds__(512, 4) void gemm_pipe(
    const short* __restrict__ A, const short* __restrict__ B,
    const float* __restrict__ bias, const float* __restrict__ res,
    float* __restrict__ outF, short* __restrict__ outB,
    short* __restrict__ outK, short* __restrict__ outV,
    int M, int N, int K)
{
  __shared__ short As[2][2][64 * 64];   // [buf][kh]: 128 rows x 64 B = 8 KB
  __shared__ short Bs[2][2][64 * 64];
  const int tid = threadIdx.x;
  const int wave = tid >> 6, lane = tid & 63;
  const int l15 = lane & 15, lhi = lane >> 4;
  const int bm = blockIdx.x, bn = blockIdx.y;
  const int wr = wave >> 2;            // 0..1: m-group (64 rows)
  const int wc = wave & 3;             // 0..3: n-group (32 cols)
  f32x4 acc[4][2] = {};

  const int srow = tid >> 2;
  const int scs = ((tid & 3) ^ ((srow >> 1) & 3)) * 16;
  const int ldst = srow * 64 + (tid & 3) * 16;
  const char* gA = (const char*)(A + (size_t)(bm * 128 + srow) * K);
  const char* gB = (const char*)(B + (size_t)(bn * 128 + srow) * K);

  const int NT = K >> 6;

  auto stagePair = [&](int buf, int kt, int kh) {
    const size_t go = (size_t)kt * 128 + kh * 64 + scs;
    glds16(gA + go, (char*)As[buf][kh] + ldst);
    glds16(gB + go, (char*)Bs[buf][kh] + ldst);
  };

  stagePair(0, 0, 0);
  stagePair(0, 0, 1);

  int buf = 0;
  for (int t = 0; t < NT; ++t) {
#pragma unroll
    for (int kh = 0; kh < 2; ++kh) {
      const bool more = (t + 1 < NT);
      if (more || kh == 0) asm volatile("s_waitcnt vmcnt(2)" ::: "memory");
      else                 asm volatile("s_waitcnt vmcnt(0)" ::: "memory");
      __builtin_amdgcn_s_barrier();
      __builtin_amdgcn_sched_barrier(0);
      s16x8 af[4], bfv[2];
#pragma unroll
      for (int m = 0; m < 4; ++m) {
        const int row = wr * 64 + m * 16 + l15;
        af[m] = *(const s16x8*)((const char*)As[buf][kh] + row * 64 +
                                ((lhi ^ ((row >> 1) & 3)) << 4));
      }
#pragma unroll
      for (int n = 0; n < 2; ++n) {
        const int row = wc * 32 + n * 16 + l15;
        bfv[n] = *(const s16x8*)((const char*)Bs[buf][kh] + row * 64 +
                                 ((lhi ^ ((row >> 1) & 3)) << 4));
      }
      if (more) stagePair(buf ^ 1, t + 1, kh);
      __builtin_amdgcn_s_setprio(1);
#pragma unroll
      for (int m = 0; m < 4; ++m)
#pragma unroll
        for (int n = 0; n < 2; ++n)
          acc[m][n] = __builtin_amdgcn_mfma_f32_16x16x32_bf16(af[m], bfv[n], acc[m][n], 0, 0, 0);
      __builtin_amdgcn_s_setprio(0);
    }
    buf ^= 1;
  }

  const int rowb = bm * 128 + wr * 64;
  const int colb = bn * 128 + wc * 32;
#pragma unroll
  for (int m = 0; m < 4; ++m) {
#pragma unroll
    for (int n = 0; n < 2; ++n) {
      if (EPI == 3) {
        const int col0 = colb + n * 16;
        const int h = col0 / 192;
        const int c0 = col0 - h * 192;
        const int region = c0 >> 6;           // 0=Q, 1=K, 2=V
        const int d = (c0 & 63) + l15;
        const int row0 = rowb + m * 16 + lhi * 4;
        const int bb = row0 >> 11, tl0 = row0 & 2047;
        const size_t bh = (size_t)bb * NH + h;
        if (region == 2) {
          s16x4 pk;
#pragma unroll
          for (int rr = 0; rr < 4; ++rr) pk[rr] = f2bf(acc[m][n][rr]);
          *(s16x4*)(outV + (bh * 64 + d) * TT + tl0) = pk;
        } else {
          short* dst = (region == 0) ? outB : outK;
          const float qs = (region == 0) ? 0.18033688011112042f : 1.0f;  // 0.125*log2(e)
#pragma unroll
          for (int rr = 0; rr < 4; ++rr)
            dst[(bh * TT + tl0 + rr) * 64 + d] = f2bf(acc[m][n][rr] * qs);
        }
      } else {
        const int col = colb + n * 16 + l15;
        const float bv = bias[col];
#pragma unroll
        for (int rr = 0; rr < 4; ++rr) {
          const int row = rowb + m * 16 + lhi * 4 + rr;
          float v = acc[m][n][rr] + bv;
          if (EPI == 1) {
            v += res[(size_t)row * N + col];
            outF[(size_t)row * N + col] = v;
          } else {
            v = 0.5f * v * (1.0f + erff(v * 0.70710678118f));
            outB[(size_t)row * N + col] = f2bf(v);
          }
        }
      }
    }
  }
}

// ---------------- flash attention v6 (r10-proven): swapped-QK^T, 16 q/wave,
// KVBLK=64, reg-prefetch staging, log2-softmax + defer-max + padded P.
#define PSTRIDE 144
#define PFRAG   2304
__global__ __launch_bounds__(256, 4) void attn_k(
    const short* __restrict__ Qb, const short* __restrict__ Kb,
    const short* __restrict__ Vtb, const int* __restrict__ mask,
    short* __restrict__ outp)
{
  const int tid = threadIdx.x, wave = tid >> 6, lane = tid & 63;
  const int l15 = lane & 15, lhi = lane >> 4;
  const int lb = blockIdx.x;
  const int bh = lb & 31, qb = lb >> 5;
  const int b = bh >> 4, h = bh & 15;
  const int qw = qb * 64 + wave * 16;

  __shared__ short Ks[64 * 64];
  __shared__ short Vt[64 * 64];
  __shared__ char Ps[4 * PFRAG];

  const short* qp = Qb + ((size_t)bh * TT + qw + l15) * 64;
  const s16x8 aq0 = *(const s16x8*)(qp + lhi * 8);
  const s16x8 aq1 = *(const s16x8*)(qp + 32 + lhi * 8);

  f32x4 o[4] = {};
  float mrow = -1e30f, lrow = 0.f;

  const int kr_s = tid >> 2, kc_s = (tid & 3) * 16;
  const int ksw = (kr_s & 7) << 4;

  const short* kgb = Kb + (size_t)bh * TT * 64 + (size_t)kr_s * 64 + kc_s;
  const short* vgb = Vtb + ((size_t)bh * 64 + kr_s) * TT + kc_s;

  s16x8 kpre[2], vpre[2];
  kpre[0] = *(const s16x8*)kgb;       kpre[1] = *(const s16x8*)(kgb + 8);
  vpre[0] = *(const s16x8*)vgb;       vpre[1] = *(const s16x8*)(vgb + 8);
  int m0 = mask[b * TT + lane];

  char* pb = Ps + wave * PFRAG + l15 * PSTRIDE;

  for (int t0 = 0; t0 < TT; t0 += 64) {
    char* krow = (char*)Ks + kr_s * 128;
    *(s16x8*)(krow + ((kc_s * 2) ^ ksw)) = kpre[0];
    *(s16x8*)(krow + ((kc_s * 2 + 16) ^ ksw)) = kpre[1];
    char* vrow = (char*)Vt + kr_s * 128;
    *(s16x8*)(vrow + ((kc_s * 2) ^ ksw)) = vpre[0];
    *(s16x8*)(vrow + ((kc_s * 2 + 16) ^ ksw)) = vpre[1];
    __syncthreads();

    const unsigned long long mb0 = __ballot(m0 != 0);
    const bool full = mb0 == ~0ULL;

    if (t0 + 64 < TT) {
      const short* kg = kgb + (size_t)(t0 + 64) * 64;
      const short* vg = vgb + t0 + 64;
      kpre[0] = *(const s16x8*)kg;  kpre[1] = *(const s16x8*)(kg + 8);
      vpre[0] = *(const s16x8*)vg;  vpre[1] = *(const s16x8*)(vg + 8);
      m0 = mask[b * TT + t0 + 64 + lane];
    }

    f32x4 sv[4];
    __builtin_amdgcn_s_setprio(1);
#pragma unroll
    for (int n = 0; n < 4; ++n) {
      const int row = n * 16 + l15;
      const int sw = (row & 7) << 4;
      const char* kr = (const char*)Ks + row * 128;
      const s16x8 a0 = *(const s16x8*)(kr + ((lhi * 16) ^ sw));
      const s16x8 a1 = *(const s16x8*)(kr + ((64 + lhi * 16) ^ sw));
      f32x4 z = {};
      z = __builtin_amdgcn_mfma_f32_16x16x32_bf16(a0, aq0, z, 0, 0, 0);
      z = __builtin_amdgcn_mfma_f32_16x16x32_bf16(a1, aq1, z, 0, 0, 0);
      sv[n] = z;
    }
    __builtin_amdgcn_s_setprio(0);

    if (!full) {
#pragma unroll
      for (int n = 0; n < 4; ++n) {
        const unsigned nib = (unsigned)(mb0 >> (n * 16 + lhi * 4)) & 0xF;
#pragma unroll
        for (int rr = 0; rr < 4; ++rr)
          if (!((nib >> rr) & 1)) sv[n][rr] = -3e38f;
      }
    }

    float mx0 = fmaxf(sv[0][0], sv[1][0]), mx1 = fmaxf(sv[0][1], sv[1][1]);
    float mx2 = fmaxf(sv[0][2], sv[1][2]), mx3 = fmaxf(sv[0][3], sv[1][3]);
    mx0 = fmaxf(mx0, fmaxf(sv[2][0], sv[3][0]));
    mx1 = fmaxf(mx1, fmaxf(sv[2][1], sv[3][1]));
    mx2 = fmaxf(mx2, fmaxf(sv[2][2], sv[3][2]));
    mx3 = fmaxf(mx3, fmaxf(sv[2][3], sv[3][3]));
    float mx = fmaxf(fmaxf(mx0, mx1), fmaxf(mx2, mx3));
    mx = fmaxf(mx, __shfl_xor(mx, 16));
    mx = fmaxf(mx, __shfl_xor(mx, 32));
    if (__any(mx > mrow + 8.0f)) {
      const float mn = fmaxf(mrow, mx);
      const float alpha = exp2f(mrow - mn);
      mrow = mn;
      lrow *= alpha;
      float ar[4];
#pragma unroll
      for (int rr = 0; rr < 4; ++rr) ar[rr] = __shfl(alpha, lhi * 4 + rr);
#pragma unroll
      for (int db = 0; db < 4; ++db)
#pragma unroll
        for (int rr = 0; rr < 4; ++rr) o[db][rr] *= ar[rr];
    }
    float s0 = 0.f, s1 = 0.f, s2 = 0.f, s3 = 0.f;
#pragma unroll
    for (int n = 0; n < 4; ++n) {
      sv[n][0] = exp2f(sv[n][0] - mrow); s0 += sv[n][0];
      sv[n][1] = exp2f(sv[n][1] - mrow); s1 += sv[n][1];
      sv[n][2] = exp2f(sv[n][2] - mrow); s2 += sv[n][2];
      sv[n][3] = exp2f(sv[n][3] - mrow); s3 += sv[n][3];
    }
    float sum = (s0 + s1) + (s2 + s3);
    sum += __shfl_xor(sum, 16);
    sum += __shfl_xor(sum, 32);
    lrow += sum;

#pragma unroll
    for (int n = 0; n < 4; ++n) {
      s16x4 pk;
#pragma unroll
      for (int rr = 0; rr < 4; ++rr) pk[rr] = f2bf(sv[n][rr]);
      *(s16x4*)(pb + n * 32 + lhi * 8) = pk;
    }
    asm volatile("s_waitcnt lgkmcnt(0)" ::: "memory");
    __builtin_amdgcn_sched_barrier(0);
    s16x8 ap[2];
    ap[0] = *(const s16x8*)(pb + lhi * 16);
    ap[1] = *(const s16x8*)(pb + 64 + lhi * 16);

    __builtin_amdgcn_s_setprio(1);
#pragma unroll
    for (int db = 0; db < 4; ++db) {
      const int d = db * 16 + l15;
      const int swv = (d & 7) << 4;
      const char* vr2 = (const char*)Vt + d * 128;
#pragma unroll
      for (int ks = 0; ks < 2; ++ks) {
        const s16x8 bv = *(const s16x8*)(vr2 + ((ks * 64 + lhi * 16) ^ swv));
        o[db] = __builtin_amdgcn_mfma_f32_16x16x32_bf16(ap[ks], bv, o[db], 0, 0, 0);
      }
    }
    __builtin_amdgcn_s_setprio(0);
    __syncthreads();
  }

  float lr[4];
#pragma unroll
  for (int rr = 0; rr < 4; ++rr) lr[rr] = __shfl(lrow, lhi * 4 + rr);
#pragma unroll
  for (int db = 0; db < 4; ++db) {
#pragma unroll
    for (int rr = 0; rr < 4; ++rr) {
      const int qg = qw + lhi * 4 + rr;
      const int cg = h * 64 + db * 16 + l15;
      outp[(size_t)(b * TT + qg) * DM + cg] = f2bf(o[db][rr] / lr[rr]);
    }
  }
}

extern "C" void kernel_launch(void* const* d_in, const int* in_sizes, int n_in,
                              void* d_out, int out_size, void* d_ws, size_t ws_size,
                              hipStream_t stream)
{
  const float* x      = (const float*)d_in[0];
  const int*   mask   = (const int*)d_in[1];
  const float* w_qkv  = (const float*)d_in[2];
  const float* w_tail = (const float*)d_in[3];
  const float* b_tail = (const float*)d_in[4];
  const float* ln1g   = (const float*)d_in[5];
  const float* ln1b   = (const float*)d_in[6];
  const float* ln2g   = (const float*)d_in[7];
  const float* ln2b   = (const float*)d_in[8];
  const float* w1     = (const float*)d_in[9];
  const float* b1     = (const float*)d_in[10];
  const float* w2     = (const float*)d_in[11];
  const float* b2     = (const float*)d_in[12];

  char* ws = (char*)d_ws;
  size_t off = 0;
  auto take = [&](size_t bytes) {
    char* p = ws + off;
    off += (bytes + 255) & ~(size_t)255;
    return p;
  };
  short* wqkvT = (short*)take((size_t)3072 * 1024 * 2);   //  6 MB
  short* wtailT= (short*)take((size_t)1024 * 1024 * 2);   //  2 MB
  short* w1T   = (short*)take((size_t)4096 * 1024 * 2);   //  8 MB
  short* w2T   = (short*)take((size_t)1024 * 4096 * 2);   //  8 MB
  short* slotZ = (short*)take((size_t)4096 * 1024 * 2);   //  8 MB
  short* qb    = (short*)take((size_t)32 * 2048 * 64 * 2);//  8 MB
  short* kb    = (short*)take((size_t)32 * 2048 * 64 * 2);//  8 MB
  short* vtb   = (short*)take((size_t)32 * 64 * 2048 * 2);//  8 MB
  float* x1    = (float*)take((size_t)4096 * 1024 * 4);   // 16 MB
  short* hbuf  = (short*)take((size_t)4096 * 4096 * 2);   // 32 MB

  // prep: weight transposes + LN1 in one launch (independent work, overlaps)
  prep_k<<<16384, 256, 0, stream>>>(w_qkv, w_tail, w1, w2,
                                    wqkvT, wtailT, w1T, w2T,
                                    x, ln1g, ln1b, slotZ);
  // QKV projection (split layout, Q pre-scaled)
  gemm_pipe<3><<<dim3(32, 24), 512, 0, stream>>>(slotZ, wqkvT, nullptr, nullptr,
                                                 nullptr, qb, kb, vtb, 4096, 3072, 1024);
  // attention
  attn_k<<<1024, 256, 0, stream>>>(qb, kb, vtb, mask, slotZ);
  // tail projection + residual -> x1 (fp32)
  gemm_pipe<1><<<dim3(32, 8), 512, 0, stream>>>(slotZ, wtailT, b_tail, x,
                                                x1, nullptr, nullptr, nullptr, 4096, 1024, 1024);
  // LN2 -> MLP
  ln_k<<<4096, 256, 0, stream>>>(x1, ln2g, ln2b, slotZ);
  gemm_pipe<2><<<dim3(32, 32), 512, 0, stream>>>(slotZ, w1T, b1, nullptr,
                                                 nullptr, hbuf, nullptr, nullptr, 4096, 4096, 1024);
  gemm_pipe<1><<<dim3(32, 8), 512, 0, stream>>>(hbuf, w2T, b2, x1,
                                                (float*)d_out, nullptr, nullptr, nullptr, 4096, 1024, 4096);
}